// Round 13
// baseline (234.737 us; speedup 1.0000x reference)
//
#include <hip/hip_runtime.h>
#include <hip/hip_bf16.h>

#define D_MODEL 1024
#define NHEADS  16
#define HD      64
#define BATCH   2
#define SEQ     2048
#define MROWS   4096
#define NQKV    1152    // 1024 Q | 64 K | 64 V

typedef short  short4v __attribute__((ext_vector_type(4)));
typedef short  short8  __attribute__((ext_vector_type(8)));
typedef float  floatx4 __attribute__((ext_vector_type(4)));
typedef unsigned uint4v __attribute__((ext_vector_type(4)));

// fp32 -> bf16 (RNE)
__device__ inline short f2bf(float f) {
  unsigned u = __builtin_bit_cast(unsigned, f);
  u = (u + 0x7FFF + ((u >> 16) & 1)) >> 16;
  return (short)u;
}

// pack two f32 -> dword of two bf16 (truncation) in ONE v_perm_b32
__device__ inline unsigned pack_trunc(float lo, float hi) {
  return __builtin_amdgcn_perm(__builtin_bit_cast(unsigned, hi),
                               __builtin_bit_cast(unsigned, lo), 0x07060302u);
}

// async 16B global -> LDS (lds base wave-uniform; HW adds lane*16)
__device__ inline void async_copy16(const short* g, short* l) {
  __builtin_amdgcn_global_load_lds(
      (const __attribute__((address_space(1))) unsigned int*)g,
      (__attribute__((address_space(3))) unsigned int*)l, 16, 0, 0);
}

// ---------------------------------------------------------------------------
// Mega prep: weight transposes (bf16 B^T pack), bias pack, x -> bf16
// ---------------------------------------------------------------------------
__global__ __launch_bounds__(256)
void prep_kernel(const float* __restrict__ x,  const float* __restrict__ Wq,
                 const float* __restrict__ Wk, const float* __restrict__ Wv,
                 const float* __restrict__ Wo, const float* __restrict__ bq,
                 const float* __restrict__ bk, const float* __restrict__ bv,
                 short* __restrict__ xb, short* __restrict__ Wqkv_t,
                 short* __restrict__ Wo_t, float* __restrict__ bqkv) {
  const int id = blockIdx.x;
  const int t  = threadIdx.x;
  if (id < 544) {
    __shared__ short Ts[64 * 72];
    const float* src; short* dst; int N, off, tile;
    if (id < 256)      { src = Wq; dst = Wqkv_t; N = 1024; off = 0;    tile = id; }
    else if (id < 272) { src = Wk; dst = Wqkv_t; N = 64;   off = 1024; tile = id - 256; }
    else if (id < 288) { src = Wv; dst = Wqkv_t; N = 64;   off = 1088; tile = id - 272; }
    else               { src = Wo; dst = Wo_t;   N = 1024; off = 0;    tile = id - 288; }
    const int k0 = (N == 1024) ? (tile & 15) * 64 : tile * 64;
    const int n0 = (N == 1024) ? (tile >> 4) * 64 : 0;
    {
      const int r = t >> 2, c = (t & 3) * 16;
      const float* s = src + (size_t)(k0 + r) * N + n0 + c;
#pragma unroll
      for (int j = 0; j < 16; j += 4) {
        float4 v = *reinterpret_cast<const float4*>(s + j);
        Ts[r * 72 + c + j + 0] = f2bf(v.x); Ts[r * 72 + c + j + 1] = f2bf(v.y);
        Ts[r * 72 + c + j + 2] = f2bf(v.z); Ts[r * 72 + c + j + 3] = f2bf(v.w);
      }
    }
    __syncthreads();
    {
      const int n = t >> 2, kc = (t & 3) * 16;
      short8 o0, o1;
#pragma unroll
      for (int j = 0; j < 8; ++j) o0[j] = Ts[(kc + j) * 72 + n];
#pragma unroll
      for (int j = 0; j < 8; ++j) o1[j] = Ts[(kc + 8 + j) * 72 + n];
      short* d = dst + (size_t)(off + n0 + n) * 1024 + k0 + kc;
      *reinterpret_cast<short8*>(d)     = o0;
      *reinterpret_cast<short8*>(d + 8) = o1;
    }
  } else if (id < 549) {
    const int i = (id - 544) * 256 + t;
    if (i < 1024)      bqkv[i] = bq[i];
    else if (i < 1088) bqkv[i] = bk[i - 1024];
    else if (i < 1152) bqkv[i] = bv[i - 1088];
  } else {
    const int i = ((id - 549) * 256 + t) * 8;
    if (i < MROWS * D_MODEL) {
      float4 a = *reinterpret_cast<const float4*>(x + i);
      float4 b = *reinterpret_cast<const float4*>(x + i + 4);
      short8 o;
      o[0] = f2bf(a.x); o[1] = f2bf(a.y); o[2] = f2bf(a.z); o[3] = f2bf(a.w);
      o[4] = f2bf(b.x); o[5] = f2bf(b.y); o[6] = f2bf(b.z); o[7] = f2bf(b.w);
      *reinterpret_cast<short8*>(xb + i) = o;
    }
  }
}

// ---------------------------------------------------------------------------
// bf16 MFMA GEMM, 128x64 tile, BK=64, PING-PONG double-buffered staging.
// CONVERGED (R5 build): 128x64/256thr best of the explored tile matrix.
// SCALE_N: cols < SCALE_N scaled by 0.125*log2(e) (folds attention scale).
// VT_FUSE: cols in [1088,1152) additionally written transposed to Vtg.
// ---------------------------------------------------------------------------
template<bool OUT_BF16, int SCALE_N, bool VT_FUSE>
__global__ __launch_bounds__(256)
void gemm_mfma_bt(const short* __restrict__ A, const short* __restrict__ Bt,
                  const float* __restrict__ bias, void* __restrict__ Cout,
                  short* __restrict__ Vtg, int M, int N, int K) {
  __shared__ short As[2][128 * 64];   // 2 x 16 KB
  __shared__ short Bs[2][64 * 64];    // 2 x  8 KB   (total 48 KB -> 3/CU)
  const int t    = threadIdx.x;
  const int w    = t >> 6;
  const int lane = t & 63;
  const int quad = lane >> 4;
  const int l16  = lane & 15;
  const int bm   = blockIdx.x * 128;
  const int bn   = blockIdx.y * 64;
  const int wm   = (w >> 1) * 64;
  const int wn   = (w & 1) * 32;

  const int srow = t >> 3;
  const int cc   = ((t & 7) ^ (srow & 7)) * 8;
  const short* gA = A  + (size_t)(bm + srow) * K + cc;
  const short* gB = Bt + (size_t)(bn + srow) * K + cc;

  floatx4 acc[4][2];
#pragma unroll
  for (int i = 0; i < 4; ++i)
#pragma unroll
    for (int j = 0; j < 2; ++j) acc[i][j] = (floatx4){0.f, 0.f, 0.f, 0.f};

  const int xr = l16 & 7;

  // prologue: stage K-step 0 into buffer 0
  async_copy16(gA, &As[0][t * 8]);
  async_copy16(gA + (size_t)32 * K, &As[0][t * 8 + 2048]);
  async_copy16(gA + (size_t)64 * K, &As[0][t * 8 + 4096]);
  async_copy16(gA + (size_t)96 * K, &As[0][t * 8 + 6144]);
  async_copy16(gB, &Bs[0][t * 8]);
  async_copy16(gB + (size_t)32 * K, &Bs[0][t * 8 + 2048]);

  int cur = 0;
  for (int k0 = 0; k0 < K; k0 += 64) {
    asm volatile("s_waitcnt vmcnt(0)" ::: "memory");
    __builtin_amdgcn_s_barrier();
    __builtin_amdgcn_sched_barrier(0);

    if (k0 + 64 < K) {
      const int nb = cur ^ 1;
      const int kn = k0 + 64;
      async_copy16(gA + kn, &As[nb][t * 8]);
      async_copy16(gA + (size_t)32 * K + kn, &As[nb][t * 8 + 2048]);
      async_copy16(gA + (size_t)64 * K + kn, &As[nb][t * 8 + 4096]);
      async_copy16(gA + (size_t)96 * K + kn, &As[nb][t * 8 + 6144]);
      async_copy16(gB + kn, &Bs[nb][t * 8]);
      async_copy16(gB + (size_t)32 * K + kn, &Bs[nb][t * 8 + 2048]);
    }
    __builtin_amdgcn_sched_barrier(0);   // pin prefetch issue before compute

    const short* Ac = As[cur];
    const short* Bc = Bs[cur];
    short8 fa0[4], fa1[4], fb0[2], fb1[2];
#pragma unroll
    for (int mi = 0; mi < 4; ++mi) {
      const int row = wm + mi * 16 + l16;
      fa0[mi] = *reinterpret_cast<const short8*>(&Ac[row * 64 + (quad ^ xr) * 8]);
      fa1[mi] = *reinterpret_cast<const short8*>(&Ac[row * 64 + ((4 + quad) ^ xr) * 8]);
    }
#pragma unroll
    for (int ni = 0; ni < 2; ++ni) {
      const int row = wn + ni * 16 + l16;
      fb0[ni] = *reinterpret_cast<const short8*>(&Bc[row * 64 + (quad ^ xr) * 8]);
      fb1[ni] = *reinterpret_cast<const short8*>(&Bc[row * 64 + ((4 + quad) ^ xr) * 8]);
    }
#pragma unroll
    for (int mi = 0; mi < 4; ++mi)
#pragma unroll
      for (int ni = 0; ni < 2; ++ni) {
        acc[mi][ni] = __builtin_amdgcn_mfma_f32_16x16x32_bf16(fa0[mi], fb0[ni], acc[mi][ni], 0, 0, 0);
        acc[mi][ni] = __builtin_amdgcn_mfma_f32_16x16x32_bf16(fa1[mi], fb1[ni], acc[mi][ni], 0, 0, 0);
      }
    cur ^= 1;
  }

#pragma unroll
  for (int ni = 0; ni < 2; ++ni) {
    const int col = bn + wn + ni * 16 + l16;
    const float bs = bias[col];
    const float sc = (col < SCALE_N) ? 0.18033688f : 1.0f;  // 0.125*log2(e)
#pragma unroll
    for (int mi = 0; mi < 4; ++mi) {
      const int row = bm + wm + mi * 16 + quad * 4;
      short4v vt4;
#pragma unroll
      for (int r = 0; r < 4; ++r) {
        const float v = (acc[mi][ni][r] + bs) * sc;
        if (OUT_BF16) {
          const short bv16 = f2bf(v);
          ((short*)Cout)[(size_t)(row + r) * N + col] = bv16;
          if (VT_FUSE) vt4[r] = bv16;
        } else {
          ((float*)Cout)[(size_t)(row + r) * N + col] = v;
        }
      }
      if (VT_FUSE && col >= 1088) {
        const int d = col - 1088;
        const int b = row >> 11, s = row & 2047;
        *reinterpret_cast<short4v*>(&Vtg[(size_t)(b * 64 + d) * SEQ + s]) = vt4;
      }
    }
  }
}

// ---------------------------------------------------------------------------
// bf16 flash MQA — ZERO-LDS, ZERO-BARRIER variant.
//  K/V per batch = 256KB+256KB: fully L2-resident (4MB/XCD). The LDS
//  staging machinery (DMA copies, vmcnt, barriers, 16 ds_read/tile) only
//  re-layouts data L2 can serve directly (guide m169: dropping V-staging
//  when L2-fits was +26%). Each lane loads its MFMA fragments straight
//  from global:
//   - K frag: lane (l16,quad) reads 16B from QKV row
//       kk + koff(kg) + ((l16>>2)&3)*8 + (l16&3)   [R3-proven key64 perm
//     folded into per-lane base; koff = {0,4,32,36}]  cols 1024+quad*8(+32)
//   - V frag: row d = dg*16+l16 of Vtg, keys kk+quad*8(+32)
//  No barriers -> waves fully independent; compiler pipelines loads across
//  tiles; TLP hides L2-hit latency. P stays in-register (lane-local).
//  __launch_bounds__(256,2): no spill risk (R1 lesson); VGPR ~150.
// ---------------------------------------------------------------------------
__global__ __launch_bounds__(256, 2)
void mqa_flash_bf16(const short* __restrict__ QKV, const short* __restrict__ Vtg,
                    short* __restrict__ Att) {
  const int bh   = blockIdx.y;
  const int b    = bh >> 4;
  const int h    = bh & 15;
  const int s0   = blockIdx.x * 128;
  const int t    = threadIdx.x;
  const int w    = t >> 6;
  const int lane = t & 63;
  const int quad = lane >> 4;
  const int l16  = lane & 15;

  // Q B-frags (pre-scaled in GEMM epilogue)
  short8 aq[2][2];
#pragma unroll
  for (int st = 0; st < 2; ++st) {
    const short* qrow = &QKV[(size_t)(b * SEQ + s0 + w * 32 + st * 16 + l16) * NQKV + h * HD];
    aq[st][0] = *reinterpret_cast<const short8*>(qrow + quad * 8);
    aq[st][1] = *reinterpret_cast<const short8*>(qrow + 32 + quad * 8);
  }

  floatx4 oacc[2][4];
  floatx4 lacc[2];
#pragma unroll
  for (int st = 0; st < 2; ++st) {
    lacc[st] = (floatx4){0.f, 0.f, 0.f, 0.f};
#pragma unroll
    for (int dg = 0; dg < 4; ++dg) oacc[st][dg] = (floatx4){0.f, 0.f, 0.f, 0.f};
  }

  short8 ones;
#pragma unroll
  for (int j = 0; j < 8; ++j) ones[j] = (short)0x3F80;  // bf16 1.0

  // per-lane fragment base pointers (permutation folded into K row index)
  const int krl = ((l16 >> 2) & 3) * 8 + (l16 & 3);   // lane part of key64
  const short* pK0 = QKV + (size_t)(b * SEQ + krl) * NQKV + 1024 + quad * 8;
  const short* pK1 = pK0 + (size_t)4  * NQKV;   // koff(kg=1)
  const short* pK2 = pK0 + (size_t)32 * NQKV;   // koff(kg=2)
  const short* pK3 = pK0 + (size_t)36 * NQKV;   // koff(kg=3)
  const short* pV0 = Vtg + (size_t)(b * 64 + l16) * SEQ + quad * 8;
  const short* pV1 = pV0 + (size_t)16 * SEQ;
  const short* pV2 = pV0 + (size_t)32 * SEQ;
  const short* pV3 = pV0 + (size_t)48 * SEQ;

  for (int kk = 0; kk < SEQ; kk += 64) {
    const size_t ko = (size_t)kk * NQKV;
    short8 kb[4][2], vb[4][2];
    kb[0][0] = *reinterpret_cast<const short8*>(pK0 + ko);
    kb[0][1] = *reinterpret_cast<const short8*>(pK0 + ko + 32);
    kb[1][0] = *reinterpret_cast<const short8*>(pK1 + ko);
    kb[1][1] = *reinterpret_cast<const short8*>(pK1 + ko + 32);
    kb[2][0] = *reinterpret_cast<const short8*>(pK2 + ko);
    kb[2][1] = *reinterpret_cast<const short8*>(pK2 + ko + 32);
    kb[3][0] = *reinterpret_cast<const short8*>(pK3 + ko);
    kb[3][1] = *reinterpret_cast<const short8*>(pK3 + ko + 32);
    vb[0][0] = *reinterpret_cast<const short8*>(pV0 + kk);
    vb[0][1] = *reinterpret_cast<const short8*>(pV0 + kk + 32);
    vb[1][0] = *reinterpret_cast<const short8*>(pV1 + kk);
    vb[1][1] = *reinterpret_cast<const short8*>(pV1 + kk + 32);
    vb[2][0] = *reinterpret_cast<const short8*>(pV2 + kk);
    vb[2][1] = *reinterpret_cast<const short8*>(pV2 + kk + 32);
    vb[3][0] = *reinterpret_cast<const short8*>(pV3 + kk);
    vb[3][1] = *reinterpret_cast<const short8*>(pV3 + kk + 32);

#pragma unroll
    for (int st = 0; st < 2; ++st) {
      // S^T = K·Q^T over permuted key rows; p = exp2(s)
      floatx4 s4[4];
#pragma unroll
      for (int kg = 0; kg < 4; ++kg) {
        s4[kg] = (floatx4){0.f, 0.f, 0.f, 0.f};
        s4[kg] = __builtin_amdgcn_mfma_f32_16x16x32_bf16(kb[kg][0], aq[st][0], s4[kg], 0, 0, 0);
        s4[kg] = __builtin_amdgcn_mfma_f32_16x16x32_bf16(kb[kg][1], aq[st][1], s4[kg], 0, 0, 0);
      }
      // lane-local P -> bf16 A-frags (keys quad*8..+7 within the 64-window)
      unsigned pk[8];
#pragma unroll
      for (int kg = 0; kg < 4; ++kg) {
        const float p0 = __builtin_exp2f(s4[kg][0]);
        const float p1 = __builtin_exp2f(s4[kg][1]);
        const float p2 = __builtin_exp2f(s4[kg][2]);
        const float p3 = __builtin_exp2f(s4[kg][3]);
        pk[kg * 2 + 0] = pack_trunc(p0, p1);
        pk[kg * 2 + 1] = pack_trunc(p2, p3);
      }
      const uint4v u0 = (uint4v){pk[0], pk[1], pk[2], pk[3]};
      const uint4v u1 = (uint4v){pk[4], pk[5], pk[6], pk[7]};
      const short8 ap0 = __builtin_bit_cast(short8, u0);
      const short8 ap1 = __builtin_bit_cast(short8, u1);

      // O += P·V ; l += P·ones
      __builtin_amdgcn_s_setprio(1);
      lacc[st] = __builtin_amdgcn_mfma_f32_16x16x32_bf16(ap0, ones, lacc[st], 0, 0, 0);
      lacc[st] = __builtin_amdgcn_mfma_f32_16x16x32_bf16(ap1, ones, lacc[st], 0, 0, 0);
#pragma unroll
      for (int dg = 0; dg < 4; ++dg) {
        oacc[st][dg] = __builtin_amdgcn_mfma_f32_16x16x32_bf16(ap0, vb[dg][0], oacc[st][dg], 0, 0, 0);
        oacc[st][dg] = __builtin_amdgcn_mfma_f32_16x16x32_bf16(ap1, vb[dg][1], oacc[st][dg], 0, 0, 0);
      }
      __builtin_amdgcn_s_setprio(0);
    }
  }

  // epilogue: final softmax divide, write bf16 Att directly
  short* At = Att + (size_t)b * SEQ * D_MODEL + h * HD;
#pragma unroll
  for (int st = 0; st < 2; ++st) {
#pragma unroll
    for (int rg = 0; rg < 4; ++rg) {
      const int q = s0 + w * 32 + st * 16 + quad * 4 + rg;
      const float inv = 1.0f / lacc[st][rg];
      short* dst = At + (size_t)q * D_MODEL + l16;
#pragma unroll
      for (int dg = 0; dg < 4; ++dg) dst[dg * 16] = f2bf(oacc[st][dg][rg] * inv);
    }
  }
}

// ---------------------------------------------------------------------------
extern "C" void kernel_launch(void* const* d_in, const int* in_sizes, int n_in,
                              void* d_out, int out_size, void* d_ws, size_t ws_size,
                              hipStream_t stream) {
  const float* x  = (const float*)d_in[0];
  const float* Wq = (const float*)d_in[1];
  const float* bq = (const float*)d_in[2];
  const float* Wk = (const float*)d_in[3];
  const float* bk = (const float*)d_in[4];
  const float* Wv = (const float*)d_in[5];
  const float* bv = (const float*)d_in[6];
  const float* Wo = (const float*)d_in[7];
  const float* bo = (const float*)d_in[8];
  float* out = (float*)d_out;

  short* Wqkv_t = (short*)d_ws;                              // 1152*1024
  short* Wo_t   = Wqkv_t + (size_t)NQKV * D_MODEL;           // 1024*1024
  short* xb     = Wo_t + (size_t)D_MODEL * D_MODEL;          // 4096*1024
  short* QKV    = xb + (size_t)MROWS * D_MODEL;              // 4096*1152
  short* Att    = QKV + (size_t)MROWS * NQKV;                // 4096*1024
  short* Vtg    = Att + (size_t)MROWS * D_MODEL;             // 2*64*2048
  float* bqkv   = (float*)(Vtg + (size_t)BATCH * HD * SEQ);  // 1152

  prep_kernel<<<2597, 256, 0, stream>>>(x, Wq, Wk, Wv, Wo, bq, bk, bv,
                                        xb, Wqkv_t, Wo_t, bqkv);

  // QKV projection; Q cols pre-scaled; V cols also written transposed (Vtg)
  gemm_mfma_bt<true, 1024, true><<<dim3(MROWS / 128, NQKV / 64), 256, 0, stream>>>(
      xb, Wqkv_t, bqkv, QKV, Vtg, MROWS, NQKV, D_MODEL);

  mqa_flash_bf16<<<dim3(SEQ / 128, BATCH * NHEADS), 256, 0, stream>>>(
      QKV, Vtg, Att);

  gemm_mfma_bt<false, 0, false><<<dim3(MROWS / 128, D_MODEL / 64), 256, 0, stream>>>(
      Att, Wo_t, bo, out, nullptr, MROWS, D_MODEL, D_MODEL);
}

// Round 14
// 166.150 us; speedup vs baseline: 1.4128x; 1.4128x over previous
//
#include <hip/hip_runtime.h>
#include <hip/hip_bf16.h>

#define D_MODEL 1024
#define NHEADS  16
#define HD      64
#define BATCH   2
#define SEQ     2048
#define MROWS   4096
#define NQKV    1152    // 1024 Q | 64 K | 64 V

typedef short  short4v __attribute__((ext_vector_type(4)));
typedef short  short8  __attribute__((ext_vector_type(8)));
typedef float  floatx4 __attribute__((ext_vector_type(4)));
typedef unsigned uint4v __attribute__((ext_vector_type(4)));

// fp32 -> bf16 (RNE)
__device__ inline short f2bf(float f) {
  unsigned u = __builtin_bit_cast(unsigned, f);
  u = (u + 0x7FFF + ((u >> 16) & 1)) >> 16;
  return (short)u;
}

// pack two f32 -> dword of two bf16 (truncation) in ONE v_perm_b32
__device__ inline unsigned pack_trunc(float lo, float hi) {
  return __builtin_amdgcn_perm(__builtin_bit_cast(unsigned, hi),
                               __builtin_bit_cast(unsigned, lo), 0x07060302u);
}

// async 16B global -> LDS (lds base wave-uniform; HW adds lane*16)
__device__ inline void async_copy16(const short* g, short* l) {
  __builtin_amdgcn_global_load_lds(
      (const __attribute__((address_space(1))) unsigned int*)g,
      (__attribute__((address_space(3))) unsigned int*)l, 16, 0, 0);
}

// ---------------------------------------------------------------------------
// Mega prep: weight transposes (bf16 B^T pack), bias pack, x -> bf16
// ---------------------------------------------------------------------------
__global__ __launch_bounds__(256)
void prep_kernel(const float* __restrict__ x,  const float* __restrict__ Wq,
                 const float* __restrict__ Wk, const float* __restrict__ Wv,
                 const float* __restrict__ Wo, const float* __restrict__ bq,
                 const float* __restrict__ bk, const float* __restrict__ bv,
                 short* __restrict__ xb, short* __restrict__ Wqkv_t,
                 short* __restrict__ Wo_t, float* __restrict__ bqkv) {
  const int id = blockIdx.x;
  const int t  = threadIdx.x;
  if (id < 544) {
    __shared__ short Ts[64 * 72];
    const float* src; short* dst; int N, off, tile;
    if (id < 256)      { src = Wq; dst = Wqkv_t; N = 1024; off = 0;    tile = id; }
    else if (id < 272) { src = Wk; dst = Wqkv_t; N = 64;   off = 1024; tile = id - 256; }
    else if (id < 288) { src = Wv; dst = Wqkv_t; N = 64;   off = 1088; tile = id - 272; }
    else               { src = Wo; dst = Wo_t;   N = 1024; off = 0;    tile = id - 288; }
    const int k0 = (N == 1024) ? (tile & 15) * 64 : tile * 64;
    const int n0 = (N == 1024) ? (tile >> 4) * 64 : 0;
    {
      const int r = t >> 2, c = (t & 3) * 16;
      const float* s = src + (size_t)(k0 + r) * N + n0 + c;
#pragma unroll
      for (int j = 0; j < 16; j += 4) {
        float4 v = *reinterpret_cast<const float4*>(s + j);
        Ts[r * 72 + c + j + 0] = f2bf(v.x); Ts[r * 72 + c + j + 1] = f2bf(v.y);
        Ts[r * 72 + c + j + 2] = f2bf(v.z); Ts[r * 72 + c + j + 3] = f2bf(v.w);
      }
    }
    __syncthreads();
    {
      const int n = t >> 2, kc = (t & 3) * 16;
      short8 o0, o1;
#pragma unroll
      for (int j = 0; j < 8; ++j) o0[j] = Ts[(kc + j) * 72 + n];
#pragma unroll
      for (int j = 0; j < 8; ++j) o1[j] = Ts[(kc + 8 + j) * 72 + n];
      short* d = dst + (size_t)(off + n0 + n) * 1024 + k0 + kc;
      *reinterpret_cast<short8*>(d)     = o0;
      *reinterpret_cast<short8*>(d + 8) = o1;
    }
  } else if (id < 549) {
    const int i = (id - 544) * 256 + t;
    if (i < 1024)      bqkv[i] = bq[i];
    else if (i < 1088) bqkv[i] = bk[i - 1024];
    else if (i < 1152) bqkv[i] = bv[i - 1088];
  } else {
    const int i = ((id - 549) * 256 + t) * 8;
    if (i < MROWS * D_MODEL) {
      float4 a = *reinterpret_cast<const float4*>(x + i);
      float4 b = *reinterpret_cast<const float4*>(x + i + 4);
      short8 o;
      o[0] = f2bf(a.x); o[1] = f2bf(a.y); o[2] = f2bf(a.z); o[3] = f2bf(a.w);
      o[4] = f2bf(b.x); o[5] = f2bf(b.y); o[6] = f2bf(b.z); o[7] = f2bf(b.w);
      *reinterpret_cast<short8*>(xb + i) = o;
    }
  }
}

// ---------------------------------------------------------------------------
// bf16 MFMA GEMM, 128x64 tile, BK=64, PING-PONG double-buffered staging.
// CONVERGED (R5 build): 128x64/256thr best of the explored tile matrix
// (128x128@512thr +5us R8; 128x128@256thr +11us R11 — small-N shapes give
// 128x128 only ~1 block/CU).
// SCALE_N: cols < SCALE_N scaled by 0.125*log2(e) (folds attention scale).
// VT_FUSE: cols in [1088,1152) additionally written transposed to Vtg.
// ---------------------------------------------------------------------------
template<bool OUT_BF16, int SCALE_N, bool VT_FUSE>
__global__ __launch_bounds__(256)
void gemm_mfma_bt(const short* __restrict__ A, const short* __restrict__ Bt,
                  const float* __restrict__ bias, void* __restrict__ Cout,
                  short* __restrict__ Vtg, int M, int N, int K) {
  __shared__ short As[2][128 * 64];   // 2 x 16 KB
  __shared__ short Bs[2][64 * 64];    // 2 x  8 KB   (total 48 KB -> 3/CU)
  const int t    = threadIdx.x;
  const int w    = t >> 6;
  const int lane = t & 63;
  const int quad = lane >> 4;
  const int l16  = lane & 15;
  const int bm   = blockIdx.x * 128;
  const int bn   = blockIdx.y * 64;
  const int wm   = (w >> 1) * 64;
  const int wn   = (w & 1) * 32;

  const int srow = t >> 3;
  const int cc   = ((t & 7) ^ (srow & 7)) * 8;
  const short* gA = A  + (size_t)(bm + srow) * K + cc;
  const short* gB = Bt + (size_t)(bn + srow) * K + cc;

  floatx4 acc[4][2];
#pragma unroll
  for (int i = 0; i < 4; ++i)
#pragma unroll
    for (int j = 0; j < 2; ++j) acc[i][j] = (floatx4){0.f, 0.f, 0.f, 0.f};

  const int xr = l16 & 7;

  // prologue: stage K-step 0 into buffer 0
  async_copy16(gA, &As[0][t * 8]);
  async_copy16(gA + (size_t)32 * K, &As[0][t * 8 + 2048]);
  async_copy16(gA + (size_t)64 * K, &As[0][t * 8 + 4096]);
  async_copy16(gA + (size_t)96 * K, &As[0][t * 8 + 6144]);
  async_copy16(gB, &Bs[0][t * 8]);
  async_copy16(gB + (size_t)32 * K, &Bs[0][t * 8 + 2048]);

  int cur = 0;
  for (int k0 = 0; k0 < K; k0 += 64) {
    asm volatile("s_waitcnt vmcnt(0)" ::: "memory");
    __builtin_amdgcn_s_barrier();
    __builtin_amdgcn_sched_barrier(0);

    if (k0 + 64 < K) {
      const int nb = cur ^ 1;
      const int kn = k0 + 64;
      async_copy16(gA + kn, &As[nb][t * 8]);
      async_copy16(gA + (size_t)32 * K + kn, &As[nb][t * 8 + 2048]);
      async_copy16(gA + (size_t)64 * K + kn, &As[nb][t * 8 + 4096]);
      async_copy16(gA + (size_t)96 * K + kn, &As[nb][t * 8 + 6144]);
      async_copy16(gB + kn, &Bs[nb][t * 8]);
      async_copy16(gB + (size_t)32 * K + kn, &Bs[nb][t * 8 + 2048]);
    }
    __builtin_amdgcn_sched_barrier(0);   // pin prefetch issue before compute

    const short* Ac = As[cur];
    const short* Bc = Bs[cur];
    short8 fa0[4], fa1[4], fb0[2], fb1[2];
#pragma unroll
    for (int mi = 0; mi < 4; ++mi) {
      const int row = wm + mi * 16 + l16;
      fa0[mi] = *reinterpret_cast<const short8*>(&Ac[row * 64 + (quad ^ xr) * 8]);
      fa1[mi] = *reinterpret_cast<const short8*>(&Ac[row * 64 + ((4 + quad) ^ xr) * 8]);
    }
#pragma unroll
    for (int ni = 0; ni < 2; ++ni) {
      const int row = wn + ni * 16 + l16;
      fb0[ni] = *reinterpret_cast<const short8*>(&Bc[row * 64 + (quad ^ xr) * 8]);
      fb1[ni] = *reinterpret_cast<const short8*>(&Bc[row * 64 + ((4 + quad) ^ xr) * 8]);
    }
#pragma unroll
    for (int mi = 0; mi < 4; ++mi)
#pragma unroll
      for (int ni = 0; ni < 2; ++ni) {
        acc[mi][ni] = __builtin_amdgcn_mfma_f32_16x16x32_bf16(fa0[mi], fb0[ni], acc[mi][ni], 0, 0, 0);
        acc[mi][ni] = __builtin_amdgcn_mfma_f32_16x16x32_bf16(fa1[mi], fb1[ni], acc[mi][ni], 0, 0, 0);
      }
    cur ^= 1;
  }

#pragma unroll
  for (int ni = 0; ni < 2; ++ni) {
    const int col = bn + wn + ni * 16 + l16;
    const float bs = bias[col];
    const float sc = (col < SCALE_N) ? 0.18033688f : 1.0f;  // 0.125*log2(e)
#pragma unroll
    for (int mi = 0; mi < 4; ++mi) {
      const int row = bm + wm + mi * 16 + quad * 4;
      short4v vt4;
#pragma unroll
      for (int r = 0; r < 4; ++r) {
        const float v = (acc[mi][ni][r] + bs) * sc;
        if (OUT_BF16) {
          const short bv16 = f2bf(v);
          ((short*)Cout)[(size_t)(row + r) * N + col] = bv16;
          if (VT_FUSE) vt4[r] = bv16;
        } else {
          ((float*)Cout)[(size_t)(row + r) * N + col] = v;
        }
      }
      if (VT_FUSE && col >= 1088) {
        const int d = col - 1088;
        const int b = row >> 11, s = row & 2047;
        *reinterpret_cast<short4v*>(&Vtg[(size_t)(b * 64 + d) * SEQ + s]) = vt4;
      }
    }
  }
}

// ---------------------------------------------------------------------------
// bf16 flash MQA — R10/R12 build, FINAL (session optimum, measured twice at
// 165.7/166.2 us total).
//  - in-register P via K-row permutation (R3): QK^T output lane (l16,quad)
//    holds exactly the 8 keys its PV A-fragment needs — P never touches LDS
//  - 128-key tiles per barrier (R9), V as two [64][64] tiles (R10: zero
//    bank conflicts; single [64][128] was 2.1M conflicts, -7us)
//  - LDS staging is REQUIRED: zero-LDS direct fragment loads (R13) hit
//    64-distinct-cacheline-per-instruction request amplification, -121%
//  - 7 structural variants (R3-R13) pinned 56-59us = D=64 2-phase floor
// ---------------------------------------------------------------------------
__global__ __launch_bounds__(256, 2)
void mqa_flash_bf16(const short* __restrict__ QKV, const short* __restrict__ Vtg,
                    short* __restrict__ Att) {
  const int bh   = blockIdx.y;
  const int b    = bh >> 4;
  const int h    = bh & 15;
  const int s0   = blockIdx.x * 128;
  const int t    = threadIdx.x;
  const int w    = t >> 6;
  const int lane = t & 63;
  const int quad = lane >> 4;
  const int l16  = lane & 15;

  __shared__ short KVs[2][16384];  // K[128][64] | V0[64][64] | V1[64][64]

  // Q B-frags (pre-scaled in GEMM epilogue)
  short8 aq[2][2];
#pragma unroll
  for (int st = 0; st < 2; ++st) {
    const short* qrow = &QKV[(size_t)(b * SEQ + s0 + w * 32 + st * 16 + l16) * NQKV + h * HD];
    aq[st][0] = *reinterpret_cast<const short8*>(qrow + quad * 8);
    aq[st][1] = *reinterpret_cast<const short8*>(qrow + 32 + quad * 8);
  }

  floatx4 oacc[2][4];
  floatx4 lacc[2];
#pragma unroll
  for (int st = 0; st < 2; ++st) {
    lacc[st] = (floatx4){0.f, 0.f, 0.f, 0.f};
#pragma unroll
    for (int dg = 0; dg < 4; ++dg) oacc[st][dg] = (floatx4){0.f, 0.f, 0.f, 0.f};
  }

  short8 ones;
#pragma unroll
  for (int j = 0; j < 8; ++j) ones[j] = (short)0x3F80;  // bf16 1.0

  // staging sources (XOR-swizzled 16B chunks), R5-proven geometry.
  const int srow = t >> 3;
  const int cc   = ((t & 7) ^ (srow & 7)) * 8;
  const int krow = ((srow >> 4) & 1) * 4 + ((srow >> 2) & 3) * 8 + (srow & 3);
  const short* gK = QKV + (size_t)(b * SEQ + krow) * NQKV + 1024 + cc;
  const short* gV = Vtg + (size_t)(b * 64 + srow) * SEQ + cc;   // d-row srow

  const int xr = l16 & 7;

#define STAGE(BUF)                                                     \
  {                                                                    \
    short* lK  = KVs[BUF] + w * 512;                                   \
    short* lV0 = KVs[BUF] + 8192  + w * 512;                           \
    short* lV1 = KVs[BUF] + 12288 + w * 512;                           \
    async_copy16(gK, lK);                                              \
    async_copy16(gK + (size_t)32 * NQKV, lK + 2048);                   \
    async_copy16(gK + (size_t)64 * NQKV, lK + 4096);                   \
    async_copy16(gK + (size_t)96 * NQKV, lK + 6144);                   \
    async_copy16(gV, lV0);                                             \
    async_copy16(gV + (size_t)32 * SEQ, lV0 + 2048);                   \
    async_copy16(gV + 64, lV1);                                        \
    async_copy16(gV + (size_t)32 * SEQ + 64, lV1 + 2048);              \
    gK += (size_t)128 * NQKV;                                          \
    gV += 128;                                                         \
  }

  // prologue: stage tile 0 (128 keys) into buf0
  STAGE(0)

  const int NT = SEQ / 128;   // 16
  int cur = 0;

  for (int it = 0; it < NT; ++it) {
    asm volatile("s_waitcnt vmcnt(0)" ::: "memory");
    __builtin_amdgcn_s_barrier();
    __builtin_amdgcn_sched_barrier(0);

    if (it + 1 < NT) STAGE(cur ^ 1)
    __builtin_amdgcn_sched_barrier(0);   // pin prefetch issue before compute

#pragma unroll
    for (int half = 0; half < 2; ++half) {
      const short* Ks = KVs[cur] + half * 4096;           // K rows half*64..
      const short* Vt = KVs[cur] + 8192 + half * 4096;    // V-half [64][64]

      short8 kb[4][2], vb[4][2];
#pragma unroll
      for (int kg = 0; kg < 4; ++kg) {
        kb[kg][0] = *reinterpret_cast<const short8*>(&Ks[(kg * 16 + l16) * 64 + (quad ^ xr) * 8]);
        kb[kg][1] = *reinterpret_cast<const short8*>(&Ks[(kg * 16 + l16) * 64 + ((4 + quad) ^ xr) * 8]);
      }
#pragma unroll
      for (int dg = 0; dg < 4; ++dg) {
        vb[dg][0] = *reinterpret_cast<const short8*>(&Vt[(dg * 16 + l16) * 64 + (quad ^ xr) * 8]);
        vb[dg][1] = *reinterpret_cast<const short8*>(&Vt[(dg * 16 + l16) * 64 + ((4 + quad) ^ xr) * 8]);
      }

#pragma unroll
      for (int st = 0; st < 2; ++st) {
        // S^T = K·Q^T over permuted key rows; p = exp2(s)
        floatx4 s4[4];
#pragma unroll
        for (int kg = 0; kg < 4; ++kg) {
          s4[kg] = (floatx4){0.f, 0.f, 0.f, 0.f};
          s4[kg] = __builtin_amdgcn_mfma_f32_16x16x32_bf16(kb[kg][0], aq[st][0], s4[kg], 0, 0, 0);
          s4[kg] = __builtin_amdgcn_mfma_f32_16x16x32_bf16(kb[kg][1], aq[st][1], s4[kg], 0, 0, 0);
        }
        // lane-local P -> bf16 A-frags (keys quad*8..+7 within half)
        unsigned pk[8];
#pragma unroll
        for (int kg = 0; kg < 4; ++kg) {
          const float p0 = __builtin_exp2f(s4[kg][0]);
          const float p1 = __builtin_exp2f(s4[kg][1]);
          const float p2 = __builtin_exp2f(s4[kg][2]);
          const float p3 = __builtin_exp2f(s4[kg][3]);
          pk[kg * 2 + 0] = pack_trunc(p0, p1);
          pk[kg * 2 + 1] = pack_trunc(p2, p3);
        }
        const uint4v u0 = (uint4v){pk[0], pk[1], pk[2], pk[3]};
        const uint4v u1 = (uint4v){pk[4], pk[5], pk[6], pk[7]};
        const short8 ap0 = __builtin_bit_cast(short8, u0);
        const short8 ap1 = __builtin_bit_cast(short8, u1);

        // O += P·V ; l += P·ones
        __builtin_amdgcn_s_setprio(1);
        lacc[st] = __builtin_amdgcn_mfma_f32_16x16x32_bf16(ap0, ones, lacc[st], 0, 0, 0);
        lacc[st] = __builtin_amdgcn_mfma_f32_16x16x32_bf16(ap1, ones, lacc[st], 0, 0, 0);
#pragma unroll
        for (int dg = 0; dg < 4; ++dg) {
          oacc[st][dg] = __builtin_amdgcn_mfma_f32_16x16x32_bf16(ap0, vb[dg][0], oacc[st][dg], 0, 0, 0);
          oacc[st][dg] = __builtin_amdgcn_mfma_f32_16x16x32_bf16(ap1, vb[dg][1], oacc[st][dg], 0, 0, 0);
        }
        __builtin_amdgcn_s_setprio(0);
      }
    }
    cur ^= 1;
  }
#undef STAGE

  // epilogue: final softmax divide, write bf16 Att directly
  short* At = Att + (size_t)b * SEQ * D_MODEL + h * HD;
#pragma unroll
  for (int st = 0; st < 2; ++st) {
#pragma unroll
    for (int rg = 0; rg < 4; ++rg) {
      const int q = s0 + w * 32 + st * 16 + quad * 4 + rg;
      const float inv = 1.0f / lacc[st][rg];
      short* dst = At + (size_t)q * D_MODEL + l16;
#pragma unroll
      for (int dg = 0; dg < 4; ++dg) dst[dg * 16] = f2bf(oacc[st][dg][rg] * inv);
    }
  }
}

// ---------------------------------------------------------------------------
extern "C" void kernel_launch(void* const* d_in, const int* in_sizes, int n_in,
                              void* d_out, int out_size, void* d_ws, size_t ws_size,
                              hipStream_t stream) {
  const float* x  = (const float*)d_in[0];
  const float* Wq = (const float*)d_in[1];
  const float* bq = (const float*)d_in[2];
  const float* Wk = (const float*)d_in[3];
  const float* bk = (const float*)d_in[4];
  const float* Wv = (const float*)d_in[5];
  const float* bv = (const float*)d_in[6];
  const float* Wo = (const float*)d_in[7];
  const float* bo = (const float*)d_in[8];
  float* out = (float*)d_out;

  short* Wqkv_t = (short*)d_ws;                              // 1152*1024
  short* Wo_t   = Wqkv_t + (size_t)NQKV * D_MODEL;           // 1024*1024
  short* xb     = Wo_t + (size_t)D_MODEL * D_MODEL;          // 4096*1024
  short* QKV    = xb + (size_t)MROWS * D_MODEL;              // 4096*1152
  short* Att    = QKV + (size_t)MROWS * NQKV;                // 4096*1024
  short* Vtg    = Att + (size_t)MROWS * D_MODEL;             // 2*64*2048
  float* bqkv   = (float*)(Vtg + (size_t)BATCH * HD * SEQ);  // 1152

  prep_kernel<<<2597, 256, 0, stream>>>(x, Wq, Wk, Wv, Wo, bq, bk, bv,
                                        xb, Wqkv_t, Wo_t, bqkv);

  // QKV projection; Q cols pre-scaled; V cols also written transposed (Vtg)
  gemm_mfma_bt<true, 1024, true><<<dim3(MROWS / 128, NQKV / 64), 256, 0, stream>>>(
      xb, Wqkv_t, bqkv, QKV, Vtg, MROWS, NQKV, D_MODEL);

  mqa_flash_bf16<<<dim3(SEQ / 128, BATCH * NHEADS), 256, 0, stream>>>(
      QKV, Vtg, Att);

  gemm_mfma_bt<false, 0, false><<<dim3(MROWS / 128, D_MODEL / 64), 256, 0, stream>>>(
      Att, Wo_t, bo, out, nullptr, MROWS, D_MODEL, D_MODEL);
}